// Round 1
// 15560.553 us; speedup vs baseline: 1.3073x; 1.3073x over previous
//
#include <hip/hip_runtime.h>

#define NPER 512
#define CDIM 256
#define BG   64
#define NB   128
#define TPB  256
#define GW   8      // graphs per cluster
#define CW   16     // channels per member block
#define WST  258    // col-major weight stride (256 + 2): bank stride 2 -> free
#define AST  10     // k-major activation stride (8 graphs + 2 pad)
#define CAP  64

// Zero the tagged exchange buffers (tags must be 0 so step-1 polls for tag 0
// succeed immediately, and so stale tags from a previous replay can't alias).
__global__ void init_ws(unsigned long long* p, int n) {
    int i = blockIdx.x * blockDim.x + threadIdx.x;
    if (i < n) p[i] = 0ULL;
}

__device__ __forceinline__ float ld_sc(const float* p) {
    return __hip_atomic_load((const float*)p, __ATOMIC_RELAXED, __HIP_MEMORY_SCOPE_AGENT);
}
__device__ __forceinline__ void st_sc(float* p, float v) {
    __hip_atomic_store(p, v, __ATOMIC_RELAXED, __HIP_MEMORY_SCOPE_AGENT);
}
// One 8B atomic store carries (value, tag) together: no fence / store-order
// assumption anywhere in the protocol.
__device__ __forceinline__ void st_tag(float* buf, int idx, float v, unsigned tg) {
    unsigned long long u = ((unsigned long long)tg << 32) |
                           (unsigned long long)__float_as_uint(v);
    __hip_atomic_store((unsigned long long*)(buf + 2 * (size_t)idx), u,
                       __ATOMIC_RELAXED, __HIP_MEMORY_SCOPE_AGENT);
}

// Poll a cluster's tagged exchange buffer until all 2048 (value,tag) pairs
// carry `tg`. Detection and data arrive in the same LLC round-trip.
// Single-buffer WAR safety: the step chain (hnew->z->agg->hnew) guarantees a
// producer writing step t has observed all step-t inputs, which implies every
// consumer finished its step t-1 reads of this buffer.
// The __syncthreads_and also serves as the block barrier that makes the
// subsequent sh_act/sh_hold restage safe vs. the previous phase's readers.
__device__ __forceinline__ void poll_tag(const float* buf, unsigned tg, int tid,
                                         float* vals) {
    unsigned long long u[8];
    int ok = 0;
    do {
        if (!ok) {
            #pragma unroll
            for (int j = 0; j < 8; ++j)
                u[j] = __hip_atomic_load(
                    (const unsigned long long*)(buf + 2 * (size_t)(j * TPB + tid)),
                    __ATOMIC_RELAXED, __HIP_MEMORY_SCOPE_AGENT);
            ok = 1;
            #pragma unroll
            for (int j = 0; j < 8; ++j) ok &= ((unsigned)(u[j] >> 32) == tg);
        }
    } while (!__syncthreads_and(ok));
    #pragma unroll
    for (int j = 0; j < 8; ++j) vals[j] = __uint_as_float((unsigned)(u[j] & 0xffffffffu));
}

__global__ __launch_bounds__(TPB, 1)
void gnn_fp32(const float* __restrict__ x,
              const float* __restrict__ W1g, const float* __restrict__ b1g,
              const float* __restrict__ W2g, const float* __restrict__ b2g,
              const float* __restrict__ wihg, const float* __restrict__ bihg,
              const float* __restrict__ whhg, const float* __restrict__ bhhg,
              const int* __restrict__ src_f, const int* __restrict__ gid_f,
              const float* __restrict__ msk_f,
              const int* __restrict__ src_b, const int* __restrict__ gid_b,
              const float* __restrict__ msk_b,
              int Kf, int Kb,
              float* __restrict__ hx,
              float* __restrict__ xh, float* __restrict__ xz,
              float* __restrict__ xa, float* __restrict__ ring)
{
    __shared__ float sh_w[128 * WST];    // col-major rows: 0-47 wih, 48-95 whh, 96-111 W1, 112-127 W2
    __shared__ float sh_act[256 * AST];
    __shared__ float sh_hold[256 * AST];
    __shared__ float sh_gi[GW * 48];
    __shared__ float sh_gh[GW * 48];
    __shared__ int   sh_list[GW * CAP];
    __shared__ int   sh_cnt[GW];
    __shared__ float sh_bih[48], sh_bhh[48], sh_b1[CW], sh_b2[CW];

    const int tid   = threadIdx.x;
    const int cl    = blockIdx.x & 7;
    const int mb    = blockIdx.x >> 3;
    const int gb    = cl * GW;
    const int cbase = mb * CW;

    float* xh_c = xh + (size_t)cl * GW * CDIM * 2;
    float* xz_c = xz + (size_t)cl * GW * CDIM * 2;
    float* xa_c = xa + (size_t)cl * GW * CDIM * 2;
    float* ring_blk = ring + (size_t)blockIdx.x * 64 * GW * CW;

    // ---- stage weights col-major into LDS, once ----
    for (int e = tid; e < 128 * 256; e += TPB) {
        int r = e >> 8, k = e & 255;
        const float* sp; int grow;
        if (r < 48)       { sp = wihg; grow = (r >> 4) * CDIM + cbase + (r & 15); }
        else if (r < 96)  { sp = whhg; grow = ((r - 48) >> 4) * CDIM + cbase + ((r - 48) & 15); }
        else if (r < 112) { sp = W1g;  grow = cbase + (r - 96); }
        else              { sp = W2g;  grow = cbase + (r - 112); }
        sh_w[r * WST + k] = sp[(size_t)grow * CDIM + k];
    }
    if (tid < 48) {
        sh_bih[tid] = bihg[(tid >> 4) * CDIM + cbase + (tid & 15)];
        sh_bhh[tid] = bhhg[(tid >> 4) * CDIM + cbase + (tid & 15)];
    } else if (tid < 64) {
        sh_b1[tid - 48] = b1g[cbase + tid - 48];
        sh_b2[tid - 48] = b2g[cbase + tid - 48];
    }
    __syncthreads();

    float keep0 = 0.f;
    const int cg = tid >> 4;
    const int cc = tid & 15;

    for (int pass = 0; pass < 2; ++pass) {
        const int* srcA   = pass ? src_b : src_f;
        const int* gidA   = pass ? gid_b : gid_f;
        const float* mskA = pass ? msk_b : msk_f;
        const int K = pass ? Kb : Kf;

        for (int s = 0; s < NPER; ++s) {
            const int node = pass ? (NPER - 1 - s) : s;
            const unsigned tg = (unsigned)(pass * NPER + s + 1);
            const bool has_prev = !(pass == 0 && s == 0);
            const int prev = (s > 0) ? (pass ? node + 1 : node - 1) : (NPER - 1);

            // ======= P1: deferred hx write; hold prefetch; poll hnew; W1 GEMM =======
            if (has_prev && tid < 128)
                st_sc(&hx[((size_t)(gb + cg) * NPER + prev) * CDIM + cbase + cc], keep0);
            float holdv[8];
            if (pass == 1 && s > 0) {           // issue early: in flight during poll
                #pragma unroll
                for (int j = 0; j < 8; ++j)
                    holdv[j] = ld_sc(&hx[((size_t)(gb + j) * NPER + node) * CDIM + tid]);
            }
            if (tid < GW) sh_cnt[tid] = 0;

            float hv[8];
            poll_tag(xh_c, tg - 1, tid, hv);    // tag 0 at (pass0,s0): zeros, unused downstream
            #pragma unroll
            for (int j = 0; j < 8; ++j) sh_act[tid * AST + j] = hv[j];
            if (pass == 0) {                    // h_old = x (read-only: cached loads)
                int sg = tid & 7, skb = (tid >> 3) << 3;
                const float* op = x + ((size_t)(gb + sg) * NPER + node) * CDIM + skb;
                float4 h0 = *(const float4*)op, h1 = *(const float4*)(op + 4);
                float* d = &sh_hold[skb * AST + sg];
                d[0] = h0.x; d[AST] = h0.y; d[2*AST] = h0.z; d[3*AST] = h0.w;
                d[4*AST] = h1.x; d[5*AST] = h1.y; d[6*AST] = h1.z; d[7*AST] = h1.w;
            } else if (s == 0) {                // h_old(node 511) == hnew from fwd end
                #pragma unroll
                for (int j = 0; j < 8; ++j) sh_hold[tid * AST + j] = hv[j];
            } else {
                #pragma unroll
                for (int j = 0; j < 8; ++j) sh_hold[tid * AST + j] = holdv[j];
            }
            __syncthreads();

            {   // W1 GEMM (rows 96..111) -> z tagged
                const int tl = tid >> 5, ks = tid & 31;
                const float* wr0 = &sh_w[(96 + tl * 2) * WST];
                const float* wr1 = wr0 + WST;
                float acc0[8] = {}, acc1[8] = {};
                #pragma unroll
                for (int j = 0; j < 8; ++j) {
                    int k = ks + j * 32;
                    float w0 = wr0[k], w1 = wr1[k];
                    const float* ap = &sh_act[k * AST];
                    #pragma unroll
                    for (int g = 0; g < 8; ++g) {
                        float a = ap[g];
                        acc0[g] += w0 * a; acc1[g] += w1 * a;
                    }
                }
                #pragma unroll
                for (int m = 1; m < 32; m <<= 1)
                    #pragma unroll
                    for (int g = 0; g < 8; ++g) {
                        acc0[g] += __shfl_xor(acc0[g], m, 64);
                        acc1[g] += __shfl_xor(acc1[g], m, 64);
                    }
                if (ks < 8) {
                    int g = ks, c0 = tl * 2;
                    float v0 = acc0[g] + sh_b1[c0];
                    float v1 = acc1[g] + sh_b1[c0 + 1];
                    st_tag(xz_c, g * CDIM + cbase + c0,     v0 > 0.f ? v0 : 0.f, tg);
                    st_tag(xz_c, g * CDIM + cbase + c0 + 1, v1 > 0.f ? v1 : 0.f, tg);
                }
            }
            // edge filter here: covers z's flight to the LLC before the P2 poll
            for (int e = tid; e < K; e += TPB) {
                size_t off = (size_t)s * K + e;
                if (mskA[off] != 0.f) {
                    int g = gidA[off] - gb;
                    if ((unsigned)g < GW) {
                        int p = atomicAdd(&sh_cnt[g], 1);
                        if (p < CAP) sh_list[g * CAP + p] = srcA[off] & 63;
                    }
                }
            }

            // ======= P2: poll z; ring = relu(W2 z); aggregate -> agg tagged =======
            float zv[8];
            poll_tag(xz_c, tg, tid, zv);
            #pragma unroll
            for (int j = 0; j < 8; ++j) sh_act[tid * AST + j] = zv[j];
            __syncthreads();

            {   // W2 GEMM (rows 112..127) -> ring[prev & 63] (block-private, cached)
                const int tl = tid >> 5, ks = tid & 31;
                const float* wr0 = &sh_w[(112 + tl * 2) * WST];
                const float* wr1 = wr0 + WST;
                float acc0[8] = {}, acc1[8] = {};
                #pragma unroll
                for (int j = 0; j < 8; ++j) {
                    int k = ks + j * 32;
                    float w0 = wr0[k], w1 = wr1[k];
                    const float* ap = &sh_act[k * AST];
                    #pragma unroll
                    for (int g = 0; g < 8; ++g) {
                        float a = ap[g];
                        acc0[g] += w0 * a; acc1[g] += w1 * a;
                    }
                }
                #pragma unroll
                for (int m = 1; m < 32; m <<= 1)
                    #pragma unroll
                    for (int g = 0; g < 8; ++g) {
                        acc0[g] += __shfl_xor(acc0[g], m, 64);
                        acc1[g] += __shfl_xor(acc1[g], m, 64);
                    }
                if (ks < 8) {
                    int g = ks, c0 = tl * 2, slot = prev & 63;
                    float v0 = acc0[g] + sh_b2[c0];
                    float v1 = acc1[g] + sh_b2[c0 + 1];
                    ring_blk[(slot * GW + g) * CW + c0]     = v0 > 0.f ? v0 : 0.f;
                    ring_blk[(slot * GW + g) * CW + c0 + 1] = v1 > 0.f ? v1 : 0.f;
                }
            }
            __syncthreads();
            if (tid < 128) {
                int n = sh_cnt[cg]; if (n > CAP) n = CAP;
                float a = 0.f;
                for (int i = 0; i < n; ++i)
                    a += ring_blk[(sh_list[cg * CAP + i] * GW + cg) * CW + cc];
                st_tag(xa_c, cg * CDIM + cbase + cc, a, tg);
            }

            // ======= P3: gh GEMM (covers agg flight); poll agg; gi GEMM; gates =======
            if (tid < 192) {  // gh GEMM (rows 48..95) -> sh_gh
                const int tl = tid >> 4, ks = tid & 15;
                const float* wr = &sh_w[(48 + tl * 4) * WST];
                float acc[4][8] = {};
                #pragma unroll 4
                for (int j = 0; j < 16; ++j) {
                    int k = ks + j * 16;
                    float w0 = wr[k], w1 = wr[WST + k], w2 = wr[2 * WST + k], w3 = wr[3 * WST + k];
                    const float* ap = &sh_hold[k * AST];
                    #pragma unroll
                    for (int g = 0; g < 8; ++g) {
                        float a = ap[g];
                        acc[0][g] += w0 * a; acc[1][g] += w1 * a;
                        acc[2][g] += w2 * a; acc[3][g] += w3 * a;
                    }
                }
                #pragma unroll
                for (int m = 1; m < 16; m <<= 1)
                    #pragma unroll
                    for (int r = 0; r < 4; ++r)
                        #pragma unroll
                        for (int g = 0; g < 8; ++g)
                            acc[r][g] += __shfl_xor(acc[r][g], m, 64);
                if (ks < 8) {
                    int g = ks;
                    #pragma unroll
                    for (int r = 0; r < 4; ++r)
                        sh_gh[g * 48 + tl * 4 + r] = acc[r][g] + sh_bhh[tl * 4 + r];
                }
            }
            float av[8];
            poll_tag(xa_c, tg, tid, av);
            #pragma unroll
            for (int j = 0; j < 8; ++j) sh_act[tid * AST + j] = av[j];
            __syncthreads();
            if (tid < 192) {  // gi GEMM (rows 0..47) -> sh_gi
                const int tl = tid >> 4, ks = tid & 15;
                const float* wr = &sh_w[(tl * 4) * WST];
                float acc[4][8] = {};
                #pragma unroll 4
                for (int j = 0; j < 16; ++j) {
                    int k = ks + j * 16;
                    float w0 = wr[k], w1 = wr[WST + k], w2 = wr[2 * WST + k], w3 = wr[3 * WST + k];
                    const float* ap = &sh_act[k * AST];
                    #pragma unroll
                    for (int g = 0; g < 8; ++g) {
                        float a = ap[g];
                        acc[0][g] += w0 * a; acc[1][g] += w1 * a;
                        acc[2][g] += w2 * a; acc[3][g] += w3 * a;
                    }
                }
                #pragma unroll
                for (int m = 1; m < 16; m <<= 1)
                    #pragma unroll
                    for (int r = 0; r < 4; ++r)
                        #pragma unroll
                        for (int g = 0; g < 8; ++g)
                            acc[r][g] += __shfl_xor(acc[r][g], m, 64);
                if (ks < 8) {
                    int g = ks;
                    #pragma unroll
                    for (int r = 0; r < 4; ++r)
                        sh_gi[g * 48 + tl * 4 + r] = acc[r][g] + sh_bih[tl * 4 + r];
                }
            }
            __syncthreads();
            if (tid < 128) {
                float ir = sh_gi[cg * 48 + cc], iz = sh_gi[cg * 48 + 16 + cc], in_ = sh_gi[cg * 48 + 32 + cc];
                float hr = sh_gh[cg * 48 + cc], hz = sh_gh[cg * 48 + 16 + cc], hn  = sh_gh[cg * 48 + 32 + cc];
                float hold = sh_hold[(cbase + cc) * AST + cg];
                float r  = 1.f / (1.f + expf(-(ir + hr)));
                float z_ = 1.f / (1.f + expf(-(iz + hz)));
                float nn = tanhf(in_ + r * hn);
                keep0 = (1.f - z_) * nn + z_ * hold;
                // pass0->pass1 hx handoff: drain our hx stores before the tag
                // that releases other blocks into pass 1.
                if (pass == 0 && s == NPER - 1)
                    asm volatile("s_waitcnt vmcnt(0)" ::: "memory");
                st_tag(xh_c, cg * CDIM + cbase + cc, keep0, tg);
            }
        }
    }
    if (tid < 128)
        st_sc(&hx[((size_t)(gb + cg) * NPER + 0) * CDIM + cbase + cc], keep0);
}

// ---------------- fallback (round-1 structure, known-correct) ----------------
__global__ __launch_bounds__(512)
void gnn_fallback(const float* __restrict__ x,
                  const float* __restrict__ W1, const float* __restrict__ b1,
                  const float* __restrict__ W2, const float* __restrict__ b2,
                  const float* __restrict__ w_ih, const float* __restrict__ b_ih,
                  const float* __restrict__ w_hh, const float* __restrict__ b_hh,
                  const int* __restrict__ src_f, const int* __restrict__ gid_f,
                  const float* __restrict__ msk_f,
                  const int* __restrict__ src_b, const int* __restrict__ gid_b,
                  const float* __restrict__ msk_b,
                  int Kf, int Kb, float* __restrict__ hx)
{
    const int b = blockIdx.x, t = threadIdx.x;
    __shared__ float sh_ring[64 * CDIM];
    __shared__ float sh_agg[CDIM], sh_hold[CDIM], sh_hnew[CDIM], sh_h1[CDIM];
    __shared__ float sh_gi[3 * CDIM], sh_gh[3 * CDIM];
    __shared__ int   sh_list[256];
    __shared__ int   sh_cnt;
    const size_t base = (size_t)b * NPER * CDIM;
    {
        const float4* x4 = (const float4*)(x + base);
        float4* h4 = (float4*)(hx + base);
        for (int i = t; i < NPER * CDIM / 4; i += 512) h4[i] = x4[i];
    }
    if (t == 0) sh_cnt = 0;
    __syncthreads();
    for (int pass = 0; pass < 2; ++pass) {
        const int* srcA = pass ? src_b : src_f;
        const int* gidA = pass ? gid_b : gid_f;
        const float* mskA = pass ? msk_b : msk_f;
        const int K = pass ? Kb : Kf;
        for (int step = 0; step < NPER; ++step) {
            const int node = pass ? (NPER - 1 - step) : step;
            if (t < CDIM / 4)
                ((float4*)sh_hold)[t] = ((const float4*)(hx + base + (size_t)node * CDIM))[t];
            for (int k = t; k < K; k += 512) {
                size_t off = (size_t)step * K + k;
                if (mskA[off] != 0.f && gidA[off] == b) {
                    int p = atomicAdd(&sh_cnt, 1);
                    if (p < 256) sh_list[p] = srcA[off] & 63;
                }
            }
            __syncthreads();
            int cnt = sh_cnt; if (cnt > 256) cnt = 256;
            if (t < CDIM) {
                float a = 0.f;
                for (int e = 0; e < cnt; ++e) a += sh_ring[sh_list[e] * CDIM + t];
                sh_agg[t] = a;
            }
            __syncthreads();
            #pragma unroll
            for (int d = 0; d < 3; ++d) {
                const int idx = t + d * 512;
                const float *wrow, *inv; float bias; float* outp;
                if (idx < 3 * CDIM) { wrow = w_ih + (size_t)idx * CDIM; inv = sh_agg; bias = b_ih[idx]; outp = &sh_gi[idx]; }
                else { int r = idx - 3 * CDIM; wrow = w_hh + (size_t)r * CDIM; inv = sh_hold; bias = b_hh[r]; outp = &sh_gh[r]; }
                float acc = 0.f;
                const float4* w4 = (const float4*)wrow; const float4* i4 = (const float4*)inv;
                #pragma unroll 8
                for (int j = 0; j < CDIM / 4; ++j) {
                    float4 w = w4[j], v = i4[j];
                    acc += w.x * v.x + w.y * v.y + w.z * v.z + w.w * v.w;
                }
                *outp = acc + bias;
            }
            __syncthreads();
            if (t < CDIM) {
                float ir = sh_gi[t], iz = sh_gi[t + CDIM], in_ = sh_gi[t + 2 * CDIM];
                float hr = sh_gh[t], hz = sh_gh[t + CDIM], hn = sh_gh[t + 2 * CDIM];
                float r = 1.f / (1.f + expf(-(ir + hr)));
                float z = 1.f / (1.f + expf(-(iz + hz)));
                float n = tanhf(in_ + r * hn);
                float hv = (1.f - z) * n + z * sh_hold[t];
                sh_hnew[t] = hv;
                hx[base + (size_t)node * CDIM + t] = hv;
            }
            if (t == 511) sh_cnt = 0;
            __syncthreads();
            if (t < CDIM) {
                const float4* w4 = (const float4*)(W1 + (size_t)t * CDIM);
                const float4* i4 = (const float4*)sh_hnew;
                float acc = 0.f;
                #pragma unroll 8
                for (int j = 0; j < CDIM / 4; ++j) {
                    float4 w = w4[j], v = i4[j];
                    acc += w.x * v.x + w.y * v.y + w.z * v.z + w.w * v.w;
                }
                acc += b1[t];
                sh_h1[t] = acc > 0.f ? acc : 0.f;
            }
            __syncthreads();
            if (t < CDIM) {
                const float4* w4 = (const float4*)(W2 + (size_t)t * CDIM);
                const float4* i4 = (const float4*)sh_h1;
                float acc = 0.f;
                #pragma unroll 8
                for (int j = 0; j < CDIM / 4; ++j) {
                    float4 w = w4[j], v = i4[j];
                    acc += w.x * v.x + w.y * v.y + w.z * v.z + w.w * v.w;
                }
                acc += b2[t];
                sh_ring[(node & 63) * CDIM + t] = acc > 0.f ? acc : 0.f;
            }
            __syncthreads();
        }
    }
}

extern "C" void kernel_launch(void* const* d_in, const int* in_sizes, int n_in,
                              void* d_out, int out_size, void* d_ws, size_t ws_size,
                              hipStream_t stream) {
    const float* x    = (const float*)d_in[0];
    const float* W1   = (const float*)d_in[1];
    const float* b1   = (const float*)d_in[2];
    const float* W2   = (const float*)d_in[3];
    const float* b2   = (const float*)d_in[4];
    const float* w_ih = (const float*)d_in[5];
    const float* b_ih = (const float*)d_in[6];
    const float* w_hh = (const float*)d_in[7];
    const float* b_hh = (const float*)d_in[8];
    const int*   src_f = (const int*)d_in[9];
    const int*   gid_f = (const int*)d_in[10];
    const float* msk_f = (const float*)d_in[11];
    const int*   src_b = (const int*)d_in[12];
    const int*   gid_b = (const int*)d_in[13];
    const float* msk_b = (const float*)d_in[14];

    const int Kf = in_sizes[9]  / NPER;
    const int Kb = in_sizes[12] / NPER;
    float* hx = (float*)d_out;

    char* ws = (char*)d_ws;
    // 4096 pad + 3 tagged exchange buffers (64 graphs x 256 ch x 8B) + ring
    const size_t need = 4096 + 3 * (size_t)BG * CDIM * 8 + (size_t)NB * 64 * GW * CW * 4;
    if (ws_size >= need) {
        float* xh   = (float*)(ws + 4096);
        float* xz   = xh + (size_t)BG * CDIM * 2;
        float* xa   = xz + (size_t)BG * CDIM * 2;
        float* ring = xa + (size_t)BG * CDIM * 2;
        // 3 * 64 * 256 = 49152 u64 pairs to zero; 192 * 256 threads covers exactly.
        init_ws<<<192, 256, 0, stream>>>((unsigned long long*)(ws + 4096), 3 * BG * CDIM);
        gnn_fp32<<<NB, TPB, 0, stream>>>(
            x, W1, b1, W2, b2, w_ih, b_ih, w_hh, b_hh,
            src_f, gid_f, msk_f, src_b, gid_b, msk_b,
            Kf, Kb, hx, xh, xz, xa, ring);
    } else {
        gnn_fallback<<<BG, 512, 0, stream>>>(
            x, W1, b1, W2, b2, w_ih, b_ih, w_hh, b_hh,
            src_f, gid_f, msk_f, src_b, gid_b, msk_b,
            Kf, Kb, hx);
    }
}